// Round 1
// baseline (447.048 us; speedup 1.0000x reference)
//
#include <hip/hip_runtime.h>
#include <hip/hip_bf16.h>

// DynamicBlockSparseMoE: top-4-of-16 expert block-sparse MoE.
// Pipeline: colsum(x) -> gating dot + top4 -> convert x to bf16 ->
// gather+transpose selected weight cols -> bf16 GEMM1 (mid) ->
// gather+transpose selected agg rows -> bf16 GEMM2 (+bias) -> f32 out.

#define BATCH 4096
#define DIN 4096
#define DOUTD 4096
#define NE 16
#define HD 1024
#define TOPK 4
#define TOTC (NE * HD)  // 16384

using bf16 = __hip_bfloat16;
typedef __attribute__((ext_vector_type(8))) short short8;
typedef __attribute__((ext_vector_type(4))) float f32x4;

__device__ inline short f2bs(float f) {
  __hip_bfloat16 h = __float2bfloat16(f);
  return *reinterpret_cast<short*>(&h);
}

// ---- gating ----------------------------------------------------------------
__global__ void k_pcol(const float* __restrict__ x, float* __restrict__ pcol) {
  int c = blockIdx.x * 256 + threadIdx.x;
  int r0 = blockIdx.y * 128;
  float s = 0.f;
  for (int r = r0; r < r0 + 128; ++r) s += x[(size_t)r * DIN + c];
  pcol[(size_t)blockIdx.y * DIN + c] = s;
}

__global__ void k_red(const float* __restrict__ pcol, float* __restrict__ colsum) {
  int c = blockIdx.x * 256 + threadIdx.x;
  float s = 0.f;
  for (int j = 0; j < 32; ++j) s += pcol[(size_t)j * DIN + c];
  colsum[c] = s;
}

__global__ void k_gate(const float* __restrict__ colsum, const float* __restrict__ gw,
                       const float* __restrict__ gb, int* __restrict__ ids) {
  __shared__ float red[4][16];
  __shared__ float gs[16];
  int t = threadIdx.x;
  int e = t & 15, kg = t >> 4;  // kg 0..15
  float p = 0.f;
  for (int k = kg; k < DIN; k += 16) p += colsum[k] * gw[(size_t)k * NE + e];
  p += __shfl_down(p, 32);
  p += __shfl_down(p, 16);
  if ((t & 63) < 16) red[t >> 6][e] = p;
  __syncthreads();
  if (t < 16) gs[t] = red[0][t] + red[1][t] + red[2][t] + red[3][t] + (float)BATCH * gb[t];
  __syncthreads();
  if (t == 0) {
    float v[16];
    #pragma unroll
    for (int i = 0; i < 16; ++i) v[i] = gs[i];
    for (int j = 0; j < TOPK; ++j) {
      int bi = 0;
      float bv = v[0];
      for (int i2 = 1; i2 < 16; ++i2) {
        if (v[i2] > bv) { bv = v[i2]; bi = i2; }
      }
      ids[j] = bi;
      v[bi] = -3.4e38f;
    }
  }
}

// ---- conversions / gathers -------------------------------------------------
__global__ void k_cvt_x(const float* __restrict__ x, bf16* __restrict__ xb) {
  size_t i = ((size_t)blockIdx.x * 256 + threadIdx.x) * 8;
  float4 v0 = *reinterpret_cast<const float4*>(x + i);
  float4 v1 = *reinterpret_cast<const float4*>(x + i + 4);
  short8 r;
  r[0] = f2bs(v0.x); r[1] = f2bs(v0.y); r[2] = f2bs(v0.z); r[3] = f2bs(v0.w);
  r[4] = f2bs(v1.x); r[5] = f2bs(v1.y); r[6] = f2bs(v1.z); r[7] = f2bs(v1.w);
  *reinterpret_cast<short8*>(reinterpret_cast<char*>(xb) + i * 2) = r;
}

// wbt[n][k] = weight[k][ids[n/1024]*1024 + n%1024]   (n,k in [0,4096))
__global__ void k_gather_w(const float* __restrict__ w, const int* __restrict__ ids,
                           bf16* __restrict__ wbt) {
  __shared__ float tile[32][33];
  int bid = blockIdx.x;
  int k0 = (bid & 127) * 32, n0 = (bid >> 7) * 32;
  int t = threadIdx.x;
  int tx = t & 31, ty = t >> 5;  // ty 0..7
  int e = ids[n0 >> 10];
  size_t wcol = (size_t)e * HD + (n0 & 1023) + tx;
  #pragma unroll
  for (int j = 0; j < 4; ++j) {
    int k = k0 + ty + j * 8;
    tile[ty + j * 8][tx] = w[(size_t)k * TOTC + wcol];
  }
  __syncthreads();
  #pragma unroll
  for (int j = 0; j < 4; ++j) {
    int n = n0 + ty + j * 8;
    wbt[(size_t)n * DIN + k0 + tx] = __float2bfloat16(tile[tx][ty + j * 8]);
  }
}

// abt[n][k] = agg_w[ids[k/1024]*1024 + k%1024][n]   (n,k in [0,4096))
__global__ void k_gather_a(const float* __restrict__ a, const int* __restrict__ ids,
                           bf16* __restrict__ abt) {
  __shared__ float tile[32][33];
  int bid = blockIdx.x;
  int k0 = (bid & 127) * 32, n0 = (bid >> 7) * 32;
  int t = threadIdx.x;
  int tx = t & 31, ty = t >> 5;
  int e = ids[k0 >> 10];
  #pragma unroll
  for (int j = 0; j < 4; ++j) {
    int k = k0 + ty + j * 8;
    size_t ar = (size_t)e * HD + (k & 1023);
    tile[ty + j * 8][tx] = a[ar * DOUTD + n0 + tx];
  }
  __syncthreads();
  #pragma unroll
  for (int j = 0; j < 4; ++j) {
    int n = n0 + ty + j * 8;
    abt[(size_t)n * DIN + k0 + tx] = __float2bfloat16(tile[tx][ty + j * 8]);
  }
}

// ---- GEMM: C(4096x4096) = A(4096x4096 row) @ Bt(4096x4096 row, N-major) ----
// 128x128 tile, BK=64, 4 waves (2x2), 16x16x32 bf16 MFMA, dbuf LDS,
// global_load_lds w=16 with pre-swizzled source (XOR (row&7)<<4 on byte 4-6).
template <int STORE_F32>
__global__ __launch_bounds__(256, 2) void k_gemm(
    const bf16* __restrict__ A, const bf16* __restrict__ Bt,
    bf16* __restrict__ Cb, float* __restrict__ Cf, const float* __restrict__ bias) {
  __shared__ char smraw[65536];  // [buf:2][A 16KB | B 16KB]
  const int t = threadIdx.x;
  const int lane = t & 63;
  const int w = t >> 6;
  const int bm = blockIdx.y * 128, bn = blockIdx.x * 128;
  const int wr = (w >> 1) * 64, wc = (w & 1) * 64;

  f32x4 acc[4][4] = {};

  const int sr = t >> 3;                 // row within 32-row chunk base
  const int sc = t & 7;                  // 16B granule
  const int scs = (sc ^ (sr & 7)) * 8;   // swizzled source offset (elements)

  auto STAGE = [&](int buf, int kt) {
    char* lbase = smraw + buf * 32768;
    #pragma unroll
    for (int i = 0; i < 4; ++i) {
      const bf16* ga = A + (size_t)(bm + i * 32 + sr) * 4096 + kt * 64 + scs;
      __builtin_amdgcn_global_load_lds(
          (const __attribute__((address_space(1))) void*)ga,
          (__attribute__((address_space(3))) void*)(lbase + i * 4096 + t * 16), 16, 0, 0);
    }
    #pragma unroll
    for (int i = 0; i < 4; ++i) {
      const bf16* gb = Bt + (size_t)(bn + i * 32 + sr) * 4096 + kt * 64 + scs;
      __builtin_amdgcn_global_load_lds(
          (const __attribute__((address_space(1))) void*)gb,
          (__attribute__((address_space(3))) void*)(lbase + 16384 + i * 4096 + t * 16), 16, 0, 0);
    }
  };

  auto COMPUTE = [&](int buf) {
    const char* sa = smraw + buf * 32768;
    const char* sb = sa + 16384;
    #pragma unroll
    for (int kk = 0; kk < 2; ++kk) {
      short8 af[4], bfr[4];
      #pragma unroll
      for (int m = 0; m < 4; ++m) {
        int row = wr + m * 16 + (lane & 15);
        int kb = (kk * 64 + ((lane >> 4) * 16)) ^ ((row & 7) * 16);
        af[m] = *reinterpret_cast<const short8*>(sa + row * 128 + kb);
      }
      #pragma unroll
      for (int n = 0; n < 4; ++n) {
        int row = wc + n * 16 + (lane & 15);
        int kb = (kk * 64 + ((lane >> 4) * 16)) ^ ((row & 7) * 16);
        bfr[n] = *reinterpret_cast<const short8*>(sb + row * 128 + kb);
      }
      #pragma unroll
      for (int m = 0; m < 4; ++m)
        #pragma unroll
        for (int n = 0; n < 4; ++n)
          acc[m][n] = __builtin_amdgcn_mfma_f32_16x16x32_bf16(af[m], bfr[n], acc[m][n], 0, 0, 0);
    }
  };

  STAGE(0, 0);
  asm volatile("s_waitcnt vmcnt(0)" ::: "memory");
  __syncthreads();
  int cur = 0;
  for (int kt = 0; kt < 63; ++kt) {
    STAGE(cur ^ 1, kt + 1);
    COMPUTE(cur);
    asm volatile("s_waitcnt vmcnt(0)" ::: "memory");
    __syncthreads();
    cur ^= 1;
  }
  COMPUTE(cur);

  const int cr = (lane >> 4) * 4;
  const int cc = lane & 15;
  #pragma unroll
  for (int m = 0; m < 4; ++m) {
    #pragma unroll
    for (int n = 0; n < 4; ++n) {
      int row = bm + wr + m * 16 + cr;
      int col = bn + wc + n * 16 + cc;
      #pragma unroll
      for (int r = 0; r < 4; ++r) {
        if constexpr (STORE_F32) {
          Cf[(size_t)(row + r) * 4096 + col] = acc[m][n][r] + bias[col];
        } else {
          Cb[(size_t)(row + r) * 4096 + col] = __float2bfloat16(acc[m][n][r]);
        }
      }
    }
  }
}

// ---- launch ----------------------------------------------------------------
extern "C" void kernel_launch(void* const* d_in, const int* in_sizes, int n_in,
                              void* d_out, int out_size, void* d_ws, size_t ws_size,
                              hipStream_t stream) {
  const float* x = (const float*)d_in[0];
  const float* gate_w = (const float*)d_in[1];
  const float* gate_b = (const float*)d_in[2];
  const float* weight = (const float*)d_in[3];
  const float* agg_w = (const float*)d_in[4];
  const float* agg_b = (const float*)d_in[5];
  float* out = (float*)d_out;
  char* ws = (char*)d_ws;

  // ws layout: pcol 512KB | colsum 16KB | ids | ... | mid 32MB @1MB | abt 32MB @33MB
  float* pcol = (float*)ws;
  float* colsum = (float*)(ws + 524288);
  int* ids = (int*)(ws + 540672);
  bf16* mid = (bf16*)(ws + (1u << 20));
  bf16* abt = (bf16*)(ws + (1u << 20) + (32u << 20));
  // scratch inside d_out (dead before GEMM2 writes it):
  bf16* xb = (bf16*)d_out;                        // 32MB
  bf16* wbt = (bf16*)((char*)d_out + (32u << 20)); // 32MB

  k_pcol<<<dim3(16, 32), 256, 0, stream>>>(x, pcol);
  k_red<<<16, 256, 0, stream>>>(pcol, colsum);
  k_gate<<<1, 256, 0, stream>>>(colsum, gate_w, gate_b, ids);
  k_cvt_x<<<8192, 256, 0, stream>>>(x, xb);
  k_gather_w<<<16384, 256, 0, stream>>>(weight, ids, wbt);
  k_gemm<0><<<dim3(32, 32), 256, 0, stream>>>(xb, wbt, mid, nullptr, nullptr);
  k_gather_a<<<16384, 256, 0, stream>>>(agg_w, ids, abt);
  k_gemm<1><<<dim3(32, 32), 256, 0, stream>>>(mid, abt, nullptr, out, agg_b);
}

// Round 2
// 410.569 us; speedup vs baseline: 1.0889x; 1.0889x over previous
//
#include <hip/hip_runtime.h>
#include <hip/hip_bf16.h>

// DynamicBlockSparseMoE: top-4-of-16 expert block-sparse MoE.
// Pipeline: colsum(x) -> gating dot + top4 -> convert x to bf16 ->
// gather+transpose selected weight cols -> bf16 GEMM1 (mid) ->
// gather+transpose selected agg rows -> bf16 GEMM2 (+bias) -> f32 out.
// GEMMs: 256x256 tile, BK=64, 8 waves, 8-phase counted-vmcnt schedule
// (T2 XOR-swizzle + T3/T4 counted vmcnt + T5 setprio).

#define BATCH 4096
#define DIN 4096
#define DOUTD 4096
#define NE 16
#define HD 1024
#define TOPK 4
#define TOTC (NE * HD)  // 16384
#define NT 64           // K-tiles of 64 over K=4096

using bf16 = __hip_bfloat16;
typedef __attribute__((ext_vector_type(8))) short short8;
typedef __attribute__((ext_vector_type(4))) float f32x4;

__device__ inline short f2bs(float f) {
  __hip_bfloat16 h = __float2bfloat16(f);
  return *reinterpret_cast<short*>(&h);
}

// ---- gating ----------------------------------------------------------------
__global__ void k_pcol(const float* __restrict__ x, float* __restrict__ pcol) {
  int c = blockIdx.x * 256 + threadIdx.x;
  int r0 = blockIdx.y * 128;
  float s = 0.f;
  for (int r = r0; r < r0 + 128; ++r) s += x[(size_t)r * DIN + c];
  pcol[(size_t)blockIdx.y * DIN + c] = s;
}

__global__ void k_red(const float* __restrict__ pcol, float* __restrict__ colsum) {
  int c = blockIdx.x * 256 + threadIdx.x;
  float s = 0.f;
  for (int j = 0; j < 32; ++j) s += pcol[(size_t)j * DIN + c];
  colsum[c] = s;
}

__global__ void k_gate(const float* __restrict__ colsum, const float* __restrict__ gw,
                       const float* __restrict__ gb, int* __restrict__ ids) {
  __shared__ float red[4][16];
  __shared__ float gs[16];
  int t = threadIdx.x;
  int e = t & 15, kg = t >> 4;
  float p = 0.f;
  for (int k = kg; k < DIN; k += 16) p += colsum[k] * gw[(size_t)k * NE + e];
  p += __shfl_down(p, 32);
  p += __shfl_down(p, 16);
  if ((t & 63) < 16) red[t >> 6][e] = p;
  __syncthreads();
  if (t < 16) gs[t] = red[0][t] + red[1][t] + red[2][t] + red[3][t] + (float)BATCH * gb[t];
  __syncthreads();
  if (t == 0) {
    float v[16];
    #pragma unroll
    for (int i = 0; i < 16; ++i) v[i] = gs[i];
    for (int j = 0; j < TOPK; ++j) {
      int bi = 0;
      float bv = v[0];
      for (int i2 = 1; i2 < 16; ++i2) {
        if (v[i2] > bv) { bv = v[i2]; bi = i2; }
      }
      ids[j] = bi;
      v[bi] = -3.4e38f;
    }
  }
}

// ---- conversions / gathers -------------------------------------------------
__global__ void k_cvt_x(const float* __restrict__ x, bf16* __restrict__ xb) {
  size_t i = ((size_t)blockIdx.x * 256 + threadIdx.x) * 8;
  float4 v0 = *reinterpret_cast<const float4*>(x + i);
  float4 v1 = *reinterpret_cast<const float4*>(x + i + 4);
  short8 r;
  r[0] = f2bs(v0.x); r[1] = f2bs(v0.y); r[2] = f2bs(v0.z); r[3] = f2bs(v0.w);
  r[4] = f2bs(v1.x); r[5] = f2bs(v1.y); r[6] = f2bs(v1.z); r[7] = f2bs(v1.w);
  *reinterpret_cast<short8*>(reinterpret_cast<char*>(xb) + i * 2) = r;
}

// wbt[n][k] = weight[k][ids[n/1024]*1024 + n%1024]
__global__ void k_gather_w(const float* __restrict__ w, const int* __restrict__ ids,
                           bf16* __restrict__ wbt) {
  __shared__ float tile[32][33];
  int bid = blockIdx.x;
  int k0 = (bid & 127) * 32, n0 = (bid >> 7) * 32;
  int t = threadIdx.x;
  int tx = t & 31, ty = t >> 5;
  int e = ids[n0 >> 10];
  size_t wcol = (size_t)e * HD + (n0 & 1023) + tx;
  #pragma unroll
  for (int j = 0; j < 4; ++j) {
    int k = k0 + ty + j * 8;
    tile[ty + j * 8][tx] = w[(size_t)k * TOTC + wcol];
  }
  __syncthreads();
  #pragma unroll
  for (int j = 0; j < 4; ++j) {
    int n = n0 + ty + j * 8;
    wbt[(size_t)n * DIN + k0 + tx] = __float2bfloat16(tile[tx][ty + j * 8]);
  }
}

// abt[n][k] = agg_w[ids[k/1024]*1024 + k%1024][n]
__global__ void k_gather_a(const float* __restrict__ a, const int* __restrict__ ids,
                           bf16* __restrict__ abt) {
  __shared__ float tile[32][33];
  int bid = blockIdx.x;
  int k0 = (bid & 127) * 32, n0 = (bid >> 7) * 32;
  int t = threadIdx.x;
  int tx = t & 31, ty = t >> 5;
  int e = ids[k0 >> 10];
  #pragma unroll
  for (int j = 0; j < 4; ++j) {
    int k = k0 + ty + j * 8;
    size_t ar = (size_t)e * HD + (k & 1023);
    tile[ty + j * 8][tx] = a[ar * DOUTD + n0 + tx];
  }
  __syncthreads();
  #pragma unroll
  for (int j = 0; j < 4; ++j) {
    int n = n0 + ty + j * 8;
    abt[(size_t)n * DIN + k0 + tx] = __float2bfloat16(tile[tx][ty + j * 8]);
  }
}

// ---- GEMM: C(4096x4096) = A @ Bt^T, 256x256 tile, BK=64, 8 waves, 8-phase --
// LDS per buffer (64KB): A half0 [128][64] @0, A half1 @16K, B half0 @32K, B half1 @48K.
// Double-buffered: 128KB. Swizzle: 16B-granule g -> g ^ (row&7) on both sides.
#define MFMA_BF16 __builtin_amdgcn_mfma_f32_16x16x32_bf16

#define MFMA16(MF0)                                                             \
  __builtin_amdgcn_s_setprio(1);                                               \
  _Pragma("unroll") for (int nf = 0; nf < 4; ++nf) {                            \
    acc[MF0][nf] = MFMA_BF16(aA0, bfrag[nf][0], acc[MF0][nf], 0, 0, 0);         \
    acc[MF0][nf] = MFMA_BF16(aA1, bfrag[nf][1], acc[MF0][nf], 0, 0, 0);         \
    acc[MF0 + 1][nf] = MFMA_BF16(aB0, bfrag[nf][0], acc[MF0 + 1][nf], 0, 0, 0); \
    acc[MF0 + 1][nf] = MFMA_BF16(aB1, bfrag[nf][1], acc[MF0 + 1][nf], 0, 0, 0); \
  }                                                                             \
  __builtin_amdgcn_s_setprio(0);

template <int STORE_F32>
__global__ __launch_bounds__(512, 2) void k_gemm8(
    const bf16* __restrict__ A, const bf16* __restrict__ Bt,
    bf16* __restrict__ Cb, float* __restrict__ Cf, const float* __restrict__ bias) {
  __shared__ __align__(16) char smraw[131072];
  const int t = threadIdx.x;
  const int lane = t & 63;
  const int w = t >> 6;          // 0..7
  const int wr = w >> 2;         // M half
  const int wc = w & 3;          // N quarter

  const int bid = blockIdx.x;
  const int swz = (bid & 7) * 32 + (bid >> 3);  // 256 wgs, 8 XCDs (bijective)
  const int bm = (swz >> 4) * 256;
  const int bn = (swz & 15) * 256;

  f32x4 acc[8][4] = {};
  short8 bfrag[4][2];

  const int srow = w * 16 + (lane >> 3);  // staging row in half-tile (load 0)
  const int sgr = lane & 7;               // 16B granule

  auto STAGE_A = [&](int buf, int half, int kt) {
    char* lb = smraw + buf * 65536 + half * 16384 + w * 2048 + lane * 16;
    #pragma unroll
    for (int i = 0; i < 2; ++i) {
      int r = srow + i * 8;
      const bf16* g = A + (size_t)(bm + half * 128 + r) * 4096 + kt * 64 + ((sgr ^ (r & 7)) * 8);
      __builtin_amdgcn_global_load_lds(
          (const __attribute__((address_space(1))) void*)g,
          (__attribute__((address_space(3))) void*)(lb + i * 1024), 16, 0, 0);
    }
  };
  auto STAGE_B = [&](int buf, int half, int kt) {
    char* lb = smraw + buf * 65536 + 32768 + half * 16384 + w * 2048 + lane * 16;
    #pragma unroll
    for (int i = 0; i < 2; ++i) {
      int r = srow + i * 8;
      const bf16* g = Bt + (size_t)(bn + half * 128 + r) * 4096 + kt * 64 + ((sgr ^ (r & 7)) * 8);
      __builtin_amdgcn_global_load_lds(
          (const __attribute__((address_space(1))) void*)g,
          (__attribute__((address_space(3))) void*)(lb + i * 1024), 16, 0, 0);
    }
  };
  auto LDA = [&](int buf, int mf, int kk) -> short8 {
    int r = mf * 16 + (lane & 15);
    int kb = ((kk * 4 + (lane >> 4)) ^ (r & 7)) * 16;
    return *reinterpret_cast<const short8*>(smraw + buf * 65536 + wr * 16384 + r * 128 + kb);
  };
  auto LDB = [&](int buf, int nf, int kk) -> short8 {
    int nc = wc * 64 + nf * 16 + (lane & 15);
    int half = nc >> 7, r = nc & 127;
    int kb = ((kk * 4 + (lane >> 4)) ^ (r & 7)) * 16;
    return *reinterpret_cast<const short8*>(smraw + buf * 65536 + 32768 + half * 16384 + r * 128 + kb);
  };

  // Prologue: B(0), A(0), B(1) issued (12 loads/wave); complete B(0),A(0).
  STAGE_B(0, 0, 0); STAGE_B(0, 1, 0);
  STAGE_A(0, 0, 0); STAGE_A(0, 1, 0);
  STAGE_B(1, 0, 1); STAGE_B(1, 1, 1);
  asm volatile("s_waitcnt vmcnt(4)" ::: "memory");
  __builtin_amdgcn_s_barrier();

  for (int j = 0; j < NT; ++j) {
    const int cur = j & 1, nxt = cur ^ 1;
    // ---- phase 0: B-frags (8) + A mf0,1 (4); stage A half0(j+1)
    {
      #pragma unroll
      for (int nf = 0; nf < 4; ++nf) {
        bfrag[nf][0] = LDB(cur, nf, 0);
        bfrag[nf][1] = LDB(cur, nf, 1);
      }
      short8 aA0 = LDA(cur, 0, 0), aA1 = LDA(cur, 0, 1);
      short8 aB0 = LDA(cur, 1, 0), aB1 = LDA(cur, 1, 1);
      if (j + 1 < NT) STAGE_A(nxt, 0, j + 1);
      __builtin_amdgcn_s_barrier();
      MFMA16(0)
      __builtin_amdgcn_s_barrier();
    }
    // ---- phase 1: A mf2,3; stage A half1(j+1)
    {
      short8 aA0 = LDA(cur, 2, 0), aA1 = LDA(cur, 2, 1);
      short8 aB0 = LDA(cur, 3, 0), aB1 = LDA(cur, 3, 1);
      if (j + 1 < NT) STAGE_A(nxt, 1, j + 1);
      __builtin_amdgcn_s_barrier();
      MFMA16(2)
      __builtin_amdgcn_s_barrier();
    }
    // ---- phase 2: A mf4,5; stage B half0(j+2) (B(j) slots dead after phase 0)
    {
      short8 aA0 = LDA(cur, 4, 0), aA1 = LDA(cur, 4, 1);
      short8 aB0 = LDA(cur, 5, 0), aB1 = LDA(cur, 5, 1);
      if (j + 2 < NT) STAGE_B(cur, 0, j + 2);
      __builtin_amdgcn_s_barrier();
      MFMA16(4)
      __builtin_amdgcn_s_barrier();
    }
    // ---- phase 3: A mf6,7; stage B half1(j+2); counted vmcnt (never 0 mid-loop)
    {
      short8 aA0 = LDA(cur, 6, 0), aA1 = LDA(cur, 6, 1);
      short8 aB0 = LDA(cur, 7, 0), aB1 = LDA(cur, 7, 1);
      if (j + 2 < NT) STAGE_B(cur, 1, j + 2);
      if (j < NT - 2) {
        asm volatile("s_waitcnt vmcnt(4)" ::: "memory");  // A(j+1),B(j+1) done; B(j+2) in flight
      } else {
        asm volatile("s_waitcnt vmcnt(0)" ::: "memory");  // tail drain
      }
      __builtin_amdgcn_s_barrier();
      MFMA16(6)
      __builtin_amdgcn_s_barrier();
    }
  }

  // Epilogue: C write. acc[mf][nf] row=bm+wr*128+mf*16+(lane>>4)*4+r, col=bn+wc*64+nf*16+(lane&15)
  const int cr = (lane >> 4) * 4;
  const int cc = lane & 15;
  #pragma unroll
  for (int mf = 0; mf < 8; ++mf) {
    #pragma unroll
    for (int nf = 0; nf < 4; ++nf) {
      int row = bm + wr * 128 + mf * 16 + cr;
      int col = bn + wc * 64 + nf * 16 + cc;
      #pragma unroll
      for (int r = 0; r < 4; ++r) {
        if constexpr (STORE_F32) {
          Cf[(size_t)(row + r) * 4096 + col] = acc[mf][nf][r] + bias[col];
        } else {
          Cb[(size_t)(row + r) * 4096 + col] = __float2bfloat16(acc[mf][nf][r]);
        }
      }
    }
  }
}

// ---- launch ----------------------------------------------------------------
extern "C" void kernel_launch(void* const* d_in, const int* in_sizes, int n_in,
                              void* d_out, int out_size, void* d_ws, size_t ws_size,
                              hipStream_t stream) {
  const float* x = (const float*)d_in[0];
  const float* gate_w = (const float*)d_in[1];
  const float* gate_b = (const float*)d_in[2];
  const float* weight = (const float*)d_in[3];
  const float* agg_w = (const float*)d_in[4];
  const float* agg_b = (const float*)d_in[5];
  float* out = (float*)d_out;
  char* ws = (char*)d_ws;

  float* pcol = (float*)ws;
  float* colsum = (float*)(ws + 524288);
  int* ids = (int*)(ws + 540672);
  bf16* mid = (bf16*)(ws + (1u << 20));
  bf16* abt = (bf16*)(ws + (1u << 20) + (32u << 20));
  // scratch inside d_out (dead before GEMM2 writes it):
  bf16* xb = (bf16*)d_out;
  bf16* wbt = (bf16*)((char*)d_out + (32u << 20));

  k_pcol<<<dim3(16, 32), 256, 0, stream>>>(x, pcol);
  k_red<<<16, 256, 0, stream>>>(pcol, colsum);
  k_gate<<<1, 256, 0, stream>>>(colsum, gate_w, gate_b, ids);
  k_cvt_x<<<8192, 256, 0, stream>>>(x, xb);
  k_gather_w<<<16384, 256, 0, stream>>>(weight, ids, wbt);
  k_gemm8<0><<<256, 512, 0, stream>>>(xb, wbt, mid, nullptr, nullptr);
  k_gather_a<<<16384, 256, 0, stream>>>(agg_w, ids, abt);
  k_gemm8<1><<<256, 512, 0, stream>>>(mid, abt, nullptr, out, agg_b);
}

// Round 3
// 385.519 us; speedup vs baseline: 1.1596x; 1.0650x over previous
//
#include <hip/hip_runtime.h>
#include <hip/hip_bf16.h>

// DynamicBlockSparseMoE: top-4-of-16 expert block-sparse MoE.
// colsum+cvt fused -> gate top4 -> gather w (f4/short8) -> GEMM1 ->
// gather agg -> GEMM2(+bias). GEMMs: 256x256, BK=64, 8 waves, 8-phase
// counted-vmcnt, branch-free steady loop (x2 K-tile unroll).

#define BATCH 4096
#define DIN 4096
#define NE 16
#define HD 1024
#define TOPK 4
#define TOTC (NE * HD)
#define NT 64

using bf16 = __hip_bfloat16;
typedef __attribute__((ext_vector_type(8))) short short8;
typedef __attribute__((ext_vector_type(4))) float f32x4;

__device__ inline short f2bs(float f) {
  __hip_bfloat16 h = __float2bfloat16(f);
  return *reinterpret_cast<short*>(&h);
}

// ---- fused column-sum + bf16 convert --------------------------------------
__global__ void k_cvtsum(const float* __restrict__ x, bf16* __restrict__ xb,
                         float* __restrict__ pcol) {
  const int lane = threadIdx.x & 63;
  const int w = threadIdx.x >> 6;  // 0..3
  const int c = blockIdx.x * 256 + lane * 4;
  const int r0 = blockIdx.y * 128 + w * 32;
  float4 s = {0.f, 0.f, 0.f, 0.f};
  for (int i = 0; i < 32; ++i) {
    size_t off = (size_t)(r0 + i) * DIN + c;
    float4 v = *reinterpret_cast<const float4*>(x + off);
    s.x += v.x; s.y += v.y; s.z += v.z; s.w += v.w;
    ushort4 b;
    b.x = (unsigned short)f2bs(v.x); b.y = (unsigned short)f2bs(v.y);
    b.z = (unsigned short)f2bs(v.z); b.w = (unsigned short)f2bs(v.w);
    *reinterpret_cast<ushort4*>(reinterpret_cast<char*>(xb) + off * 2) = b;
  }
  *reinterpret_cast<float4*>(pcol + (size_t)(blockIdx.y * 4 + w) * DIN + c) = s;
}

__global__ void k_red(const float* __restrict__ pcol, float* __restrict__ colsum) {
  int c = blockIdx.x * 256 + threadIdx.x;
  float s = 0.f;
  for (int j = 0; j < 128; ++j) s += pcol[(size_t)j * DIN + c];
  colsum[c] = s;
}

__global__ void k_gate(const float* __restrict__ colsum, const float* __restrict__ gw,
                       const float* __restrict__ gb, int* __restrict__ ids) {
  __shared__ float red[4][16];
  __shared__ float gs[16];
  int t = threadIdx.x;
  int e = t & 15, kg = t >> 4;
  float p = 0.f;
  for (int k = kg; k < DIN; k += 16) p += colsum[k] * gw[(size_t)k * NE + e];
  p += __shfl_down(p, 32);
  p += __shfl_down(p, 16);
  if ((t & 63) < 16) red[t >> 6][e] = p;
  __syncthreads();
  if (t < 16) gs[t] = red[0][t] + red[1][t] + red[2][t] + red[3][t] + (float)BATCH * gb[t];
  __syncthreads();
  if (t == 0) {
    float v[16];
    #pragma unroll
    for (int i = 0; i < 16; ++i) v[i] = gs[i];
    for (int j = 0; j < TOPK; ++j) {
      int bi = 0;
      float bv = v[0];
      for (int i2 = 1; i2 < 16; ++i2)
        if (v[i2] > bv) { bv = v[i2]; bi = i2; }
      ids[j] = bi;
      v[bi] = -3.4e38f;
    }
  }
}

// ---- gathers: 64x64 tile, float4 loads, pad-65 LDS transpose, short8 writes
// wbt[n][k] = bf16(weight[k][ids[n/1024]*1024 + n%1024])
__global__ void k_gather_w(const float* __restrict__ w, const int* __restrict__ ids,
                           bf16* __restrict__ wbt) {
  __shared__ float tile[64 * 65];
  const int k0 = (blockIdx.x & 63) * 64;
  const int n0 = (blockIdx.x >> 6) * 64;
  const int t = threadIdx.x;
  const int e = ids[n0 >> 10];
  const int wc0 = e * HD + (n0 & 1023);
  const int tc = t & 15, kr = t >> 4;
  #pragma unroll
  for (int j = 0; j < 4; ++j) {
    int kk = kr + j * 16;
    float4 v = *reinterpret_cast<const float4*>(w + (size_t)(k0 + kk) * TOTC + wc0 + tc * 4);
    float* dst = &tile[kk * 65 + tc * 4];
    dst[0] = v.x; dst[1] = v.y; dst[2] = v.z; dst[3] = v.w;
  }
  __syncthreads();
  const int tk = t & 7, nr0 = t >> 3;
  #pragma unroll
  for (int i = 0; i < 2; ++i) {
    int n = n0 + nr0 + i * 32;
    short8 r;
    #pragma unroll
    for (int m = 0; m < 8; ++m) r[m] = f2bs(tile[(tk * 8 + m) * 65 + nr0 + i * 32]);
    *reinterpret_cast<short8*>(wbt + (size_t)n * DIN + k0 + tk * 8) = r;
  }
}

// abt[n][k] = bf16(agg_w[ids[k/1024]*1024 + k%1024][n])
__global__ void k_gather_a(const float* __restrict__ a, const int* __restrict__ ids,
                           bf16* __restrict__ abt) {
  __shared__ float tile[64 * 65];
  const int k0 = (blockIdx.x & 63) * 64;
  const int n0 = (blockIdx.x >> 6) * 64;
  const int t = threadIdx.x;
  const int e = ids[k0 >> 10];
  const int ar0 = e * HD + (k0 & 1023);
  const int tc = t & 15, kr = t >> 4;
  #pragma unroll
  for (int j = 0; j < 4; ++j) {
    int kk = kr + j * 16;
    float4 v = *reinterpret_cast<const float4*>(a + (size_t)(ar0 + kk) * 4096 + n0 + tc * 4);
    float* dst = &tile[kk * 65 + tc * 4];
    dst[0] = v.x; dst[1] = v.y; dst[2] = v.z; dst[3] = v.w;
  }
  __syncthreads();
  const int tk = t & 7, nr0 = t >> 3;
  #pragma unroll
  for (int i = 0; i < 2; ++i) {
    int n = n0 + nr0 + i * 32;
    short8 r;
    #pragma unroll
    for (int m = 0; m < 8; ++m) r[m] = f2bs(tile[(tk * 8 + m) * 65 + nr0 + i * 32]);
    *reinterpret_cast<short8*>(abt + (size_t)n * DIN + k0 + tk * 8) = r;
  }
}

// ---- GEMM: 256x256 tile, BK=64, 8 waves, 8-phase, branch-free steady loop --
#define MFMA_BF16 __builtin_amdgcn_mfma_f32_16x16x32_bf16
#define VM4 asm volatile("s_waitcnt vmcnt(4)" ::: "memory")
#define VM0 asm volatile("s_waitcnt vmcnt(0)" ::: "memory")
#define NOST ((void)0)

#define PH(BUF, Q, STG, GATE)                                                   \
  do {                                                                          \
    if ((Q) == 0) {                                                             \
      _Pragma("unroll") for (int nf = 0; nf < 4; ++nf) {                        \
        bfrag[nf][0] = LDB(BUF, nf, 0);                                         \
        bfrag[nf][1] = LDB(BUF, nf, 1);                                         \
      }                                                                         \
    }                                                                           \
    short8 aA0 = LDA(BUF, 2 * (Q), 0), aA1 = LDA(BUF, 2 * (Q), 1);              \
    short8 aB0 = LDA(BUF, 2 * (Q) + 1, 0), aB1 = LDA(BUF, 2 * (Q) + 1, 1);      \
    STG;                                                                        \
    GATE;                                                                       \
    __builtin_amdgcn_s_barrier();                                               \
    __builtin_amdgcn_s_setprio(1);                                              \
    _Pragma("unroll") for (int nf = 0; nf < 4; ++nf) {                          \
      acc[2 * (Q)][nf] = MFMA_BF16(aA0, bfrag[nf][0], acc[2 * (Q)][nf], 0, 0, 0);       \
      acc[2 * (Q)][nf] = MFMA_BF16(aA1, bfrag[nf][1], acc[2 * (Q)][nf], 0, 0, 0);       \
      acc[2 * (Q) + 1][nf] = MFMA_BF16(aB0, bfrag[nf][0], acc[2 * (Q) + 1][nf], 0, 0, 0); \
      acc[2 * (Q) + 1][nf] = MFMA_BF16(aB1, bfrag[nf][1], acc[2 * (Q) + 1][nf], 0, 0, 0); \
    }                                                                           \
    __builtin_amdgcn_s_setprio(0);                                              \
    __builtin_amdgcn_s_barrier();                                               \
  } while (0)

template <int STORE_F32>
__global__ __launch_bounds__(512, 2) void k_gemm8(
    const bf16* __restrict__ A, const bf16* __restrict__ Bt,
    bf16* __restrict__ Cb, float* __restrict__ Cf, const float* __restrict__ bias) {
  __shared__ __align__(16) char smraw[131072];
  const int t = threadIdx.x;
  const int lane = t & 63;
  const int w = t >> 6;
  const int wr = w >> 2;
  const int wc = w & 3;

  const int bid = blockIdx.x;
  const int swz = (bid & 7) * 32 + (bid >> 3);
  const int bm = (swz >> 4) * 256;
  const int bn = (swz & 15) * 256;

  f32x4 acc[8][4] = {};
  short8 bfrag[4][2];

  const int srow = w * 16 + (lane >> 3);
  const int sgr = lane & 7;

  auto STAGE_A = [&](int buf, int half, int kt) {
    char* lb = smraw + buf * 65536 + half * 16384 + w * 2048 + lane * 16;
    #pragma unroll
    for (int i = 0; i < 2; ++i) {
      int r = srow + i * 8;
      const bf16* g = A + (size_t)(bm + half * 128 + r) * 4096 + kt * 64 + ((sgr ^ (r & 7)) * 8);
      __builtin_amdgcn_global_load_lds(
          (const __attribute__((address_space(1))) void*)g,
          (__attribute__((address_space(3))) void*)(lb + i * 1024), 16, 0, 0);
    }
  };
  auto STAGE_B = [&](int buf, int half, int kt) {
    char* lb = smraw + buf * 65536 + 32768 + half * 16384 + w * 2048 + lane * 16;
    #pragma unroll
    for (int i = 0; i < 2; ++i) {
      int r = srow + i * 8;
      const bf16* g = Bt + (size_t)(bn + half * 128 + r) * 4096 + kt * 64 + ((sgr ^ (r & 7)) * 8);
      __builtin_amdgcn_global_load_lds(
          (const __attribute__((address_space(1))) void*)g,
          (__attribute__((address_space(3))) void*)(lb + i * 1024), 16, 0, 0);
    }
  };
  auto LDA = [&](int buf, int mf, int kk) -> short8 {
    int r = mf * 16 + (lane & 15);
    int kb = ((kk * 4 + (lane >> 4)) ^ (r & 7)) * 16;
    return *reinterpret_cast<const short8*>(smraw + buf * 65536 + wr * 16384 + r * 128 + kb);
  };
  auto LDB = [&](int buf, int nf, int kk) -> short8 {
    int nc = wc * 64 + nf * 16 + (lane & 15);
    int half = nc >> 7, r = nc & 127;
    int kb = ((kk * 4 + (lane >> 4)) ^ (r & 7)) * 16;
    return *reinterpret_cast<const short8*>(smraw + buf * 65536 + 32768 + half * 16384 + r * 128 + kb);
  };

  // Prologue: B(0), A(0) -> buf0; B(1) -> buf1. Complete oldest 8 (B0,A0).
  STAGE_B(0, 0, 0); STAGE_B(0, 1, 0);
  STAGE_A(0, 0, 0); STAGE_A(0, 1, 0);
  STAGE_B(1, 0, 1); STAGE_B(1, 1, 1);
  VM4;
  __builtin_amdgcn_s_barrier();

  // Steady: tiles a=2t (buf0) and a+1 (buf1); stages A(a+1), B(a+2), A(a+2), B(a+3).
  for (int tt = 0; tt < 31; ++tt) {
    const int a = 2 * tt;
    PH(0, 0, STAGE_A(1, 0, a + 1), NOST);
    PH(0, 1, STAGE_A(1, 1, a + 1), NOST);
    PH(0, 2, STAGE_B(0, 0, a + 2), NOST);
    PH(0, 3, STAGE_B(0, 1, a + 2), VM4);
    PH(1, 0, STAGE_A(0, 0, a + 2), NOST);
    PH(1, 1, STAGE_A(0, 1, a + 2), NOST);
    PH(1, 2, STAGE_B(1, 0, a + 3), NOST);
    PH(1, 3, STAGE_B(1, 1, a + 3), VM4);
  }
  // Tail: tiles 62 (buf0), 63 (buf1). A(63) staged in ph1-2, then drain.
  PH(0, 0, STAGE_A(1, 0, 63), NOST);
  PH(0, 1, STAGE_A(1, 1, 63), NOST);
  PH(0, 2, NOST, NOST);
  PH(0, 3, NOST, VM0);
  PH(1, 0, NOST, NOST);
  PH(1, 1, NOST, NOST);
  PH(1, 2, NOST, NOST);
  PH(1, 3, NOST, NOST);

  const int cr = (lane >> 4) * 4;
  const int cc = lane & 15;
  #pragma unroll
  for (int mf = 0; mf < 8; ++mf) {
    #pragma unroll
    for (int nf = 0; nf < 4; ++nf) {
      int row = bm + wr * 128 + mf * 16 + cr;
      int col = bn + wc * 64 + nf * 16 + cc;
      #pragma unroll
      for (int r = 0; r < 4; ++r) {
        if constexpr (STORE_F32) {
          Cf[(size_t)(row + r) * 4096 + col] = acc[mf][nf][r] + bias[col];
        } else {
          Cb[(size_t)(row + r) * 4096 + col] = __float2bfloat16(acc[mf][nf][r]);
        }
      }
    }
  }
}

// ---- launch ----------------------------------------------------------------
extern "C" void kernel_launch(void* const* d_in, const int* in_sizes, int n_in,
                              void* d_out, int out_size, void* d_ws, size_t ws_size,
                              hipStream_t stream) {
  const float* x = (const float*)d_in[0];
  const float* gate_w = (const float*)d_in[1];
  const float* gate_b = (const float*)d_in[2];
  const float* weight = (const float*)d_in[3];
  const float* agg_w = (const float*)d_in[4];
  const float* agg_b = (const float*)d_in[5];
  float* out = (float*)d_out;
  char* ws = (char*)d_ws;

  // ws: pcol 2MB @0 | colsum 16KB @2MB | ids @2MB+16KB | mid 32MB @4MB | abt 32MB @36MB
  float* pcol = (float*)ws;
  float* colsum = (float*)(ws + (2u << 20));
  int* ids = (int*)(ws + (2u << 20) + 16384);
  bf16* mid = (bf16*)(ws + (4u << 20));
  bf16* abt = (bf16*)(ws + (36u << 20));
  // scratch inside d_out (dead before GEMM2 writes it):
  bf16* xb = (bf16*)d_out;
  bf16* wbt = (bf16*)((char*)d_out + (32u << 20));

  k_cvtsum<<<dim3(16, 32), 256, 0, stream>>>(x, xb, pcol);
  k_red<<<16, 256, 0, stream>>>(pcol, colsum);
  k_gate<<<1, 256, 0, stream>>>(colsum, gate_w, gate_b, ids);
  k_gather_w<<<4096, 256, 0, stream>>>(weight, ids, wbt);
  k_gemm8<0><<<256, 512, 0, stream>>>(xb, wbt, mid, nullptr, nullptr);
  k_gather_a<<<4096, 256, 0, stream>>>(agg_w, ids, abt);
  k_gemm8<1><<<256, 512, 0, stream>>>(mid, abt, nullptr, out, agg_b);
}